// Round 11
// baseline (655.428 us; speedup 1.0000x reference)
//
#include <hip/hip_runtime.h>
#include <hip/hip_bf16.h>
#include <cstddef>

#define L_SEQ   4096
#define BATCH   32
#define TOFF    1024
#define TBUF    3072
#define NLAYERS 30

typedef __attribute__((ext_vector_type(8))) _Float16 half8;
typedef __attribute__((ext_vector_type(4))) float f32x4;

static const size_t HSZ = (size_t)BATCH * TBUF * 64;   // fp16 elements per h buffer

// layer-kernel LDS: ONE 32 KB region, overlaid in phases:
//   phase 1: W1 [128 n][128 k] fp16, stride 256B, swizzled          (32 KB)
//   phase 2 (after B2): z [64 rows][64 ch] fp16, stride 128B, swz   (8 KB)
//   phase 3 (after B3): delta [64 rows][64 ch] fp32, stride 256B    (16 KB)
// z reads (GEMM2) and delta reads (epilogue) are wave-private rows -> only
// 3 barriers total; epilogue needs no barrier (in-order DS within wave).

__device__ inline float fast_sigmoid(float x) {
  x = fminf(fmaxf(x, -30.f), 30.f);
  return __builtin_amdgcn_rcpf(1.f + __expf(-x));
}
__device__ inline float fast_tanh(float x) {
  x = fminf(fmaxf(x, -15.f), 15.f);
  float e = __expf(-2.f * x);
  return (1.f - e) * __builtin_amdgcn_rcpf(1.f + e);
}
__device__ inline half8 lds_frag(const char* smem, int row, int kk, int rowstride) {
  int byte = row * rowstride + kk * 2;
  byte ^= (row & 7) << 4;
  return *(const half8*)(smem + byte);
}

// ---------------------------------------------------------------------------
// prep: fp16-pack W1 = [30][n=128 (f|g)][k=128 (hprev|hcur)], Wr; zero skip
// ---------------------------------------------------------------------------
__global__ __launch_bounds__(256) void prep_kernel(
    const float* __restrict__ dil_w, const float* __restrict__ gate_w,
    const float* __restrict__ res_w,
    _Float16* __restrict__ W1h, _Float16* __restrict__ Wrh,
    float* __restrict__ skip_last)
{
  int idx = blockIdx.x * 256 + threadIdx.x;
  if (idx < NLAYERS * 128 * 128) {
    int l = idx >> 14, r = idx & 16383, n = r >> 7, k = r & 127;
    const float* src = (n < 64) ? dil_w : gate_w;
    int oc = n & 63;
    float v = src[(((size_t)l * 64 + oc) * 64 + (k & 63)) * 2 + (k >> 6)];
    W1h[idx] = (_Float16)v;
  }
  if (idx < NLAYERS * 64 * 64) Wrh[idx] = (_Float16)res_w[idx];
  if (idx < BATCH * 64) skip_last[idx] = 0.f;
}

// ---------------------------------------------------------------------------
// input 1x1 conv: fp32 compute, fp16 h out via LDS bounce (coalesced stores)
// ---------------------------------------------------------------------------
__global__ __launch_bounds__(256) void input_conv_kernel(
    const float* __restrict__ x, const float* __restrict__ w,
    const float* __restrict__ bias, _Float16* __restrict__ h)
{
  __shared__ char lds[32768];
  int b = blockIdx.y;
  int t0b = 1027 + blockIdx.x * 256;
  int t = t0b + threadIdx.x;
  if (t < L_SEQ) {
    const float* xp = x + ((size_t)b * L_SEQ + t) * 32;
    float xin[32];
#pragma unroll
    for (int j = 0; j < 8; ++j) {
      float4 v = ((const float4*)xp)[j];
      xin[4*j+0] = v.x; xin[4*j+1] = v.y; xin[4*j+2] = v.z; xin[4*j+3] = v.w;
    }
#pragma unroll
    for (int q = 0; q < 8; ++q) {
      half8 pk;
#pragma unroll 2
      for (int o = 0; o < 8; ++o) {
        int oc = q * 8 + o;
        float a0 = bias[oc], a1 = 0.f;
#pragma unroll
        for (int k = 0; k < 32; k += 2) {
          a0 += w[oc * 32 + k]     * xin[k];
          a1 += w[oc * 32 + k + 1] * xin[k + 1];
        }
        pk[o] = (_Float16)(a0 + a1);
      }
      int byte = threadIdx.x * 128 + ((q ^ (threadIdx.x & 7)) * 16);
      *(half8*)(lds + byte) = pk;
    }
  }
  __syncthreads();
  _Float16* hb = h + (size_t)b * TBUF * 64;
#pragma unroll
  for (int p = 0; p < 8; ++p) {
    int B = (p * 256 + threadIdx.x) * 16;
    int row = B >> 7;
    int q = (B >> 4) & 7;
    int tg = t0b + row;
    if (tg < L_SEQ) {
      half8 v = *(const half8*)(lds + row * 128 + ((q ^ (row & 7)) * 16));
      *(half8*)(hb + (size_t)(tg - TOFF) * 64 + q * 8) = v;
    }
  }
}

// ---------------------------------------------------------------------------
// fused MFMA layer (fp16): block = 64 positions x 1 batch, 4 waves, 32 KB LDS.
// A-fragments direct from global. tail block: skip tap at virtual t = L.
// ---------------------------------------------------------------------------
__global__ __launch_bounds__(256, 4) void layer_kernel(
    const _Float16* __restrict__ hin, _Float16* __restrict__ hout,
    const _Float16* __restrict__ W1h, const _Float16* __restrict__ Wrh,
    const float* __restrict__ dil_w, const float* __restrict__ gate_w,
    const float* __restrict__ skip_w,
    const float* __restrict__ dil_b, const float* __restrict__ gate_b,
    const float* __restrict__ res_b, const float* __restrict__ skip_b,
    float* __restrict__ skip_last, int layer, int d, int tstart)
{
  extern __shared__ char smem[];
  const int b = blockIdx.y;
  const int tid = threadIdx.x;

  if (blockIdx.x == gridDim.x - 1) {
    // ---- skip tail at t=L: z uses only tap0 at h[L-d] ----
    float* hp = (float*)smem;
    float* zl = hp + 64;
    if (tid < 64)
      hp[tid] = (float)hin[((size_t)b * TBUF + (L_SEQ - d - TOFF)) * 64 + tid];
    __syncthreads();
    if (tid < 64) {
      int dc = tid;
      float f = dil_b[layer * 64 + dc], gg = gate_b[layer * 64 + dc];
      const float* wd = dil_w  + (size_t)(layer * 64 + dc) * 128;
      const float* wg = gate_w + (size_t)(layer * 64 + dc) * 128;
      for (int ic = 0; ic < 64; ++ic) {
        f  += wd[ic * 2] * hp[ic];
        gg += wg[ic * 2] * hp[ic];
      }
      zl[dc] = fast_tanh(f) * fast_sigmoid(gg);
    }
    __syncthreads();
    if (tid < 64) {
      int co = tid;
      float s = skip_b[layer * 64 + co];
      const float* wsk = skip_w + (size_t)(layer * 64 + co) * 64;
      for (int dc = 0; dc < 64; ++dc) s += wsk[dc] * zl[dc];
      skip_last[b * 64 + co] += s;   // race-free: launches serialize layers
    }
    return;
  }

  const int t0 = tstart + blockIdx.x * 64;
  const _Float16* hb = hin + (size_t)b * TBUF * 64;
  const int lane = tid & 63;
  const int wv   = tid >> 6;
  const int r0   = wv * 16;
  const int lcol = lane & 15;
  const int lg   = lane >> 4;

  // ---- A fragments direct from global (issued before barrier; latency
  //      hides under W1 staging) ----
  int trow = t0 + r0 + lcol; if (trow >= L_SEQ) trow = L_SEQ - 1;  // masked at out
  half8 a[4];
#pragma unroll
  for (int s = 0; s < 4; ++s) {          // s<2: hprev(t-d) | s>=2: hcur(t)
    int tsrc = (s < 2) ? (trow - d) : trow;
    a[s] = *(const half8*)(hb + (size_t)(tsrc - TOFF) * 64 + (s & 1) * 32 + lg * 8);
  }
  // ---- Wr fragments (global, L2-hot) ----
  half8 wr[4][2];
  const _Float16* wrp = Wrh + (size_t)layer * 4096;
#pragma unroll
  for (int j2 = 0; j2 < 4; ++j2)
#pragma unroll
    for (int s2 = 0; s2 < 2; ++s2)
      wr[j2][s2] = *(const half8*)(wrp + (j2 * 16 + lcol) * 64 + s2 * 32 + lg * 8);

  // ---- stage W1 -> LDS [128 n][128 k], swizzled (128 B / thread) ----
  {
    int n = tid >> 1, half = tid & 1;
    const half8* src = (const half8*)(W1h + (size_t)layer * 16384 + n * 128 + half * 64);
#pragma unroll
    for (int c = 0; c < 8; ++c) {
      half8 pk = src[c];
      int byte = (n * 256 + half * 128 + c * 16) ^ ((n & 7) << 4);
      *(half8*)(smem + byte) = pk;
    }
  }
  __syncthreads();   // B1: W1 visible

  // ---- GEMM1 ----
  f32x4 cf[8];
#pragma unroll
  for (int j = 0; j < 8; ++j) {
    int n = j * 16 + lcol;
    float bias = (n < 64) ? dil_b[layer * 64 + n] : gate_b[layer * 64 + n - 64];
    cf[j] = (f32x4){bias, bias, bias, bias};
  }
#pragma unroll
  for (int s = 0; s < 4; ++s) {
#pragma unroll
    for (int j = 0; j < 8; ++j) {
      half8 bb = lds_frag(smem, j * 16 + lcol, s * 32 + lg * 8, 256);
      cf[j] = __builtin_amdgcn_mfma_f32_16x16x32_f16(a[s], bb, cf[j], 0, 0, 0);
    }
  }
  __syncthreads();   // B2: all W1 reads done; region becomes z

  // ---- activation -> z (fp16, [64 rows][64 ch], 128B stride, swizzled) ----
#pragma unroll
  for (int j = 0; j < 4; ++j) {
#pragma unroll
    for (int r = 0; r < 4; ++r) {
      float z = fast_tanh(cf[j][r]) * fast_sigmoid(cf[j + 4][r]);
      int row = r0 + lg * 4 + r;            // C layout: row=(lane>>4)*4+reg
      int byte = (row * 128 + (j * 16 + lcol) * 2) ^ ((row & 7) << 4);
      *(_Float16*)(smem + byte) = (_Float16)z;
    }
  }

  // ---- GEMM2 (z reads are own-wave rows: in-order DS, no barrier) ----
  f32x4 c2[4];
#pragma unroll
  for (int j2 = 0; j2 < 4; ++j2) {
    float bias = res_b[layer * 64 + j2 * 16 + lcol];
    c2[j2] = (f32x4){bias, bias, bias, bias};
  }
#pragma unroll
  for (int s2 = 0; s2 < 2; ++s2) {
    half8 a2 = lds_frag(smem, r0 + lcol, s2 * 32 + lg * 8, 128);
#pragma unroll
    for (int j2 = 0; j2 < 4; ++j2)
      c2[j2] = __builtin_amdgcn_mfma_f32_16x16x32_f16(a2, wr[j2][s2], c2[j2], 0, 0, 0);
  }
  __syncthreads();   // B3: all z reads done; region becomes delta

  // ---- delta -> LDS (fp32 [64 rows][64 ch], 256B stride, swizzled) ----
#pragma unroll
  for (int j2 = 0; j2 < 4; ++j2) {
#pragma unroll
    for (int r = 0; r < 4; ++r) {
      int row = r0 + lg * 4 + r;
      int byte = (row * 256 + (j2 * 16 + lcol) * 4) ^ ((row & 7) << 4);
      *(float*)(smem + byte) = c2[j2][r];
    }
  }
  // ---- epilogue (wave-private rows; in-order DS, no barrier):
  //      hout = hcur(global, L2-hot) + delta, coalesced 32B stores ----
  {
    int row = tid >> 2, part = tid & 3;    // wave w: rows 16w..16w+15 = own delta
    int t = t0 + row;
    if (t < L_SEQ) {
      float dl[16];
#pragma unroll
      for (int g = 0; g < 4; ++g) {
        int byte = (row * 256 + part * 64 + g * 16) ^ ((row & 7) << 4);
        float4 v = *(const float4*)(smem + byte);
        dl[4*g+0] = v.x; dl[4*g+1] = v.y; dl[4*g+2] = v.z; dl[4*g+3] = v.w;
      }
      const _Float16* hc = hb + (size_t)(t - TOFF) * 64 + part * 16;
      half8 hc0 = *(const half8*)hc;
      half8 hc1 = *(const half8*)(hc + 8);
      half8 o0, o1;
#pragma unroll
      for (int e = 0; e < 8; ++e) {
        o0[e] = (_Float16)((float)hc0[e] + dl[e]);
        o1[e] = (_Float16)((float)hc1[e] + dl[8 + e]);
      }
      _Float16* dst = hout + ((size_t)b * TBUF + t - TOFF) * 64 + part * 16;
      *(half8*)dst = o0;
      *(half8*)(dst + 8) = o1;
    }
  }
}

// ---------------------------------------------------------------------------
// final head: relu -> end1 (64->128) -> relu -> mean/lv -> vol
// ---------------------------------------------------------------------------
__global__ __launch_bounds__(256) void final_kernel(
    const float* __restrict__ skip_last,
    const float* __restrict__ e1w, const float* __restrict__ e1b,
    const float* __restrict__ mw,  const float* __restrict__ mb,
    const float* __restrict__ lw,  const float* __restrict__ lb,
    float* __restrict__ out)
{
  __shared__ float rm[8][32], rl[8][32];
  int b  = threadIdx.x & 31;
  int eg = threadIdx.x >> 5;
  float y1[64];
  const float4* yp = (const float4*)(skip_last + b * 64);
#pragma unroll
  for (int q = 0; q < 16; ++q) {
    float4 v = yp[q];
    y1[4*q+0] = fmaxf(v.x, 0.f); y1[4*q+1] = fmaxf(v.y, 0.f);
    y1[4*q+2] = fmaxf(v.z, 0.f); y1[4*q+3] = fmaxf(v.w, 0.f);
  }
  float mp = 0.f, lp = 0.f;
  for (int ei = 0; ei < 16; ++ei) {
    int e = eg * 16 + ei;
    const float4* wp = (const float4*)(e1w + e * 64);
    float a0 = e1b[e], a1 = 0.f;
#pragma unroll
    for (int q = 0; q < 16; ++q) {
      float4 w4 = wp[q];
      a0 += w4.x * y1[4*q+0] + w4.z * y1[4*q+2];
      a1 += w4.y * y1[4*q+1] + w4.w * y1[4*q+3];
    }
    float a = fmaxf(a0 + a1, 0.f);
    mp += mw[e] * a;
    lp += lw[e] * a;
  }
  rm[eg][b] = mp; rl[eg][b] = lp;
  __syncthreads();
  if (threadIdx.x < 32) {
    int bb = threadIdx.x;
    float m = mb[0], l = lb[0];
#pragma unroll
    for (int g = 0; g < 8; ++g) { m += rm[g][bb]; l += rl[g][bb]; }
    out[bb]      = m;
    out[32 + bb] = l;
    out[64 + bb] = expf(0.5f * l);
  }
}

// ---------------------------------------------------------------------------
extern "C" void kernel_launch(void* const* d_in, const int* in_sizes, int n_in,
                              void* d_out, int out_size, void* d_ws, size_t ws_size,
                              hipStream_t stream)
{
  const float* x       = (const float*)d_in[0];
  const float* input_w = (const float*)d_in[1];
  const float* input_b = (const float*)d_in[2];
  const float* dil_w   = (const float*)d_in[3];
  const float* dil_b   = (const float*)d_in[4];
  const float* gate_w  = (const float*)d_in[5];
  const float* gate_b  = (const float*)d_in[6];
  const float* skip_w  = (const float*)d_in[7];
  const float* skip_b  = (const float*)d_in[8];
  const float* res_w   = (const float*)d_in[9];
  const float* res_b   = (const float*)d_in[10];
  const float* e1w     = (const float*)d_in[11];
  const float* e1b     = (const float*)d_in[12];
  const float* mw      = (const float*)d_in[13];
  const float* mb      = (const float*)d_in[14];
  const float* lw      = (const float*)d_in[15];
  const float* lb      = (const float*)d_in[16];
  float* out = (float*)d_out;

  _Float16* hA        = (_Float16*)d_ws;
  _Float16* hB        = hA + HSZ;
  float*    skip_last = (float*)(hB + HSZ);
  _Float16* W1h       = (_Float16*)(skip_last + BATCH * 64);
  _Float16* Wrh       = W1h + (size_t)NLAYERS * 128 * 128;

  int dil[NLAYERS];
  int R[NLAYERS + 1];
  for (int blk = 0; blk < 3; ++blk)
    for (int l = 0; l < 10; ++l) dil[blk * 10 + l] = 1 << l;
  R[NLAYERS] = L_SEQ;
  for (int i = NLAYERS - 1; i >= 0; --i) R[i] = R[i + 1] - dil[i];
  // R[0] == 1027

  prep_kernel<<<(NLAYERS * 128 * 128 + 255) / 256, 256, 0, stream>>>(
      dil_w, gate_w, res_w, W1h, Wrh, skip_last);

  {
    int nt = L_SEQ - R[0];  // 3069
    dim3 g((nt + 255) / 256, BATCH);
    input_conv_kernel<<<g, 256, 0, stream>>>(x, input_w, input_b, hA);
  }

  _Float16* hin  = hA;
  _Float16* hout = hB;
  for (int i = 0; i < NLAYERS; ++i) {
    int nt = L_SEQ - R[i + 1];            // normal positions (0 for last layer)
    dim3 g((nt + 63) / 64 + 1, BATCH);    // +1 tail block for skip @ t=L
    layer_kernel<<<g, 256, 32768, stream>>>(
        hin, hout, W1h, Wrh,
        dil_w, gate_w, skip_w,
        dil_b, gate_b, res_b, skip_b,
        skip_last, i, dil[i], R[i + 1]);
    _Float16* tmp = hin; hin = hout; hout = tmp;
  }

  final_kernel<<<1, 256, 0, stream>>>(skip_last, e1w, e1b, mw, mb, lw, lb, out);
}